// Round 7
// baseline (180.427 us; speedup 1.0000x reference)
//
#include <hip/hip_runtime.h>

#define PI_F 3.14159265358979f
#define NPAD 576
#define KSPLIT 8

__device__ __forceinline__ float2 cadd(float2 a, float2 b){ return make_float2(a.x+b.x, a.y+b.y); }
__device__ __forceinline__ float2 csub(float2 a, float2 b){ return make_float2(a.x-b.x, a.y-b.y); }
__device__ __forceinline__ float2 cmul(float2 a, float2 b){ return make_float2(a.x*b.x - a.y*b.y, a.x*b.y + a.y*b.x); }
__device__ __forceinline__ float2 shfl2(float2 v, int srcLane) {
    return make_float2(__shfl(v.x, srcLane), __shfl(v.y, srcLane));
}

// XOR swizzle on complex index for FFT ping-pong buffers
#define PH(i) ((i) ^ ((((unsigned)(i))>>5)&7))

// wave-local "barrier": buffers are wave-private, DS ops retire in-order per wave.
__device__ __forceinline__ void lgkm_sync() {
    asm volatile("s_waitcnt lgkmcnt(0)" ::: "memory");
    __builtin_amdgcn_sched_barrier(0);
}

// ---------------- kernel A: softmax -> W (normalized weights, f32) ----------------
__global__ __launch_bounds__(256) void ksoftw(const float* __restrict__ sel,
                                              float* __restrict__ Wout)
{
    const int row = blockIdx.x;
    const int tid = threadIdx.x;
    const float4* p4 = (const float4*)(sel + (size_t)row * 4096);
    float4 v[4];
    float mx = -3.0e38f;
#pragma unroll
    for (int i = 0; i < 4; ++i) {
        v[i] = p4[tid + (i<<8)];
        mx = fmaxf(mx, fmaxf(fmaxf(v[i].x, v[i].y), fmaxf(v[i].z, v[i].w)));
    }
#pragma unroll
    for (int o = 32; o >= 1; o >>= 1) mx = fmaxf(mx, __shfl_xor(mx, o));
    __shared__ float red[8];
    const int wv = tid >> 6;
    if ((tid & 63) == 0) red[wv] = mx;
    __syncthreads();
    mx = fmaxf(fmaxf(red[0], red[1]), fmaxf(red[2], red[3]));
    float s = 0.0f;
#pragma unroll
    for (int i = 0; i < 4; ++i) {
        s += __expf(v[i].x - mx) + __expf(v[i].y - mx) + __expf(v[i].z - mx) + __expf(v[i].w - mx);
    }
#pragma unroll
    for (int o = 32; o >= 1; o >>= 1) s += __shfl_xor(s, o);
    if ((tid & 63) == 0) red[4 + wv] = s;
    __syncthreads();
    const float inv = 1.0f / (red[4] + red[5] + red[6] + red[7]);
    float4* w4 = (float4*)(Wout + (size_t)row * 4096);
#pragma unroll
    for (int i = 0; i < 4; ++i) {
        float4 e;
        e.x = __expf(v[i].x - mx) * inv;
        e.y = __expf(v[i].y - mx) * inv;
        e.z = __expf(v[i].z - mx) * inv;
        e.w = __expf(v[i].w - mx) * inv;
        w4[tid + (i<<8)] = e;
    }
}

// ---------------- kernel B: split-K GEMM  Cpart[ks] = W[:, ks] @ items[ks, :] ----------------
__global__ __launch_bounds__(256, 2) void kgemm2(const float* __restrict__ W,
                                                 const float* __restrict__ items,
                                                 float* __restrict__ Cpart)
{
    __shared__ float As[16][68];   // [k][m]
    __shared__ float Bs[16][72];   // [k][n]
    const int tid = threadIdx.x;
    const int r0 = blockIdx.x * 64;
    const int c0 = blockIdx.y * 64;
    const int k0 = blockIdx.z * (4096 / KSPLIT);

    const int ty = tid >> 4;
    const int tx = tid & 15;
    const int am = tid >> 2;
    const int ak = (tid & 3) << 2;
    const int brow = tid >> 4;
    const int bc4 = (tid & 15) << 2;
    const int bcol = c0 + bc4;

    const float* wp = W + (size_t)(r0 + am) * 4096 + k0 + ak;

    float acc[4][4] = {{0.f}};

    for (int kt = 0; kt < (4096 / KSPLIT) / 16; ++kt) {
        const int kb = kt << 4;
        const float4 a = *(const float4*)(wp + kb);
        const float* ip = items + (size_t)(k0 + kb + brow) * 514 + bcol;
        float2 b01 = (bcol     < 514) ? *(const float2*)(ip)     : make_float2(0.f, 0.f);
        float2 b23 = (bcol + 2 < 514) ? *(const float2*)(ip + 2) : make_float2(0.f, 0.f);
        __syncthreads();
        As[ak + 0][am] = a.x;
        As[ak + 1][am] = a.y;
        As[ak + 2][am] = a.z;
        As[ak + 3][am] = a.w;
        *(float4*)&Bs[brow][bc4] = make_float4(b01.x, b01.y, b23.x, b23.y);
        __syncthreads();
#pragma unroll
        for (int kk = 0; kk < 16; ++kk) {
            const float4 av = *(const float4*)&As[kk][ty << 2];
            const float4 bv = *(const float4*)&Bs[kk][tx << 2];
            acc[0][0] = fmaf(av.x, bv.x, acc[0][0]);
            acc[0][1] = fmaf(av.x, bv.y, acc[0][1]);
            acc[0][2] = fmaf(av.x, bv.z, acc[0][2]);
            acc[0][3] = fmaf(av.x, bv.w, acc[0][3]);
            acc[1][0] = fmaf(av.y, bv.x, acc[1][0]);
            acc[1][1] = fmaf(av.y, bv.y, acc[1][1]);
            acc[1][2] = fmaf(av.y, bv.z, acc[1][2]);
            acc[1][3] = fmaf(av.y, bv.w, acc[1][3]);
            acc[2][0] = fmaf(av.z, bv.x, acc[2][0]);
            acc[2][1] = fmaf(av.z, bv.y, acc[2][1]);
            acc[2][2] = fmaf(av.z, bv.z, acc[2][2]);
            acc[2][3] = fmaf(av.z, bv.w, acc[2][3]);
            acc[3][0] = fmaf(av.w, bv.x, acc[3][0]);
            acc[3][1] = fmaf(av.w, bv.y, acc[3][1]);
            acc[3][2] = fmaf(av.w, bv.z, acc[3][2]);
            acc[3][3] = fmaf(av.w, bv.w, acc[3][3]);
        }
    }

    float* cp = Cpart + (size_t)blockIdx.z * (1024 * NPAD)
                      + (size_t)(r0 + (ty << 2)) * NPAD + c0 + (tx << 2);
#pragma unroll
    for (int i = 0; i < 4; ++i) {
        *(float4*)(cp + (size_t)i * NPAD) = make_float4(acc[i][0], acc[i][1], acc[i][2], acc[i][3]);
    }
}

// ---------------- kernel B2: reduce split-K + transform -> P planes ----------------
__global__ __launch_bounds__(256) void ktrans(const float* __restrict__ Cpart,
                                              float* __restrict__ P)
{
    const int m = blockIdx.x;
    float* Lp = P;
    float* Mp = P + 1024*257;
    float* Cp = P + 2*1024*257;
    float* Sp = P + 3*1024*257;
    for (int c = threadIdx.x; c < 514; c += 256) {
        const float* cp = Cpart + (size_t)m * NPAD + c;
        float x = 0.f;
#pragma unroll
        for (int ks = 0; ks < KSPLIT; ++ks) x += cp[(size_t)ks * (1024 * NPAD)];
        if (c < 257) {
            float mm = 0.9999f / (1.0f + __expf(-x));
            int idx = m*257 + c;
            Lp[idx] = __log2f(mm);
            Mp[idx] = mm;
        } else {
            int idx = m*257 + (c - 257);
            float e2 = __expf(2.0f*x);
            float th = (e2 - 1.0f) / (e2 + 1.0f);
            float ph = PI_F * th;
            float sn, cs;
            __sincosf(ph, &sn, &cs);
            Cp[idx] = cs;
            Sp[idx] = sn;
        }
    }
}

// ---------------- kernel C: 2-way ILP — each wave runs TWO independent j-chains ----------
// grid = 1024 items * 8 jgroups; 4 independent waves per block; chains (j, j+8) interleaved.
__global__ __launch_bounds__(256) void kres(const float* __restrict__ P, float* __restrict__ out)
{
    const int tid = threadIdx.x;
    const int lane = tid & 63;
    const int wv = tid >> 6;
    const int item = blockIdx.x >> 3;
    const int jg = blockIdx.x & 7;

    __shared__ float2 bufA_s[4][2][256];
    __shared__ float2 bufB_s[4][2][256];

    // stage twiddles e^{+2πi idx/256} — pure functions of lane, hoisted to regs
    const float A256 = 6.283185307179586f / 256.0f;
    float2 s0w1, s0w2, s0w3, s1w1, s1w2, s1w3, s2w1, s2w2, s2w3;
    {
        float s, c;
        const int p1 = (lane >> 2) << 2;
        const int p2 = (lane >> 4) << 4;
        __sincosf(A256 * (float)lane,     &s, &c); s0w1 = make_float2(c, s);
        __sincosf(A256 * (float)(2*lane), &s, &c); s0w2 = make_float2(c, s);
        __sincosf(A256 * (float)(3*lane), &s, &c); s0w3 = make_float2(c, s);
        __sincosf(A256 * (float)p1,       &s, &c); s1w1 = make_float2(c, s);
        __sincosf(A256 * (float)(2*p1),   &s, &c); s1w2 = make_float2(c, s);
        __sincosf(A256 * (float)(3*p1),   &s, &c); s1w3 = make_float2(c, s);
        __sincosf(A256 * (float)p2,       &s, &c); s2w1 = make_float2(c, s);
        __sincosf(A256 * (float)(2*p2),   &s, &c); s2w2 = make_float2(c, s);
        __sincosf(A256 * (float)(3*p2),   &s, &c); s2w3 = make_float2(c, s);
    }
    // half-size-packing twiddles e^{+2πi k/512}, k = lane+64r
    float2 zwr[4];
#pragma unroll
    for (int r = 0; r < 4; ++r) {
        float s, c;
        __sincosf((6.283185307179586f/512.0f) * (float)(lane + (r<<6)), &s, &c);
        zwr[r] = make_float2(c, s);
    }

    const float* Lp = P;
    const float* Mp = P + 1024*257;
    const float* Cp = P + 2*1024*257;
    const float* Sp = P + 3*1024*257;
    const int pb = item * 257;

    float l[4], mg[4], cf[4], sf[4];
#pragma unroll
    for (int r = 0; r < 4; ++r) {
        int c = lane + (r<<6);
        l[r]  = Lp[pb + c];
        mg[r] = Mp[pb + c];
        cf[r] = Cp[pb + c];
        sf[r] = Sp[pb + c];
    }
    const float l6 = Lp[pb + 256];
    const float m6 = Mp[pb + 256];
    const float c6 = Cp[pb + 256];

    float2* outbase = (float2*)out + (size_t)item * 16384;
    const int dn = (lane + 63) & 63;
    const int up = (lane + 1) & 63;
    const int mlane = (64 - lane) & 63;

    for (int t = 0; t < 2; ++t) {
        // chain q: j = jg*16 + wv + 4t + 8q  (q=0,1) — independent dependency chains
        float2 S[2][4], V[2][4], H[2][4], Z[2][4];
        float S6[2], V6[2], H6[2];
        int jq[2];

#pragma unroll
        for (int q = 0; q < 2; ++q) {
            const int j = jg*16 + wv + (t<<2) + (q<<3);
            jq[q] = j;
            const float gf = (j > 0) ? 1.0f : 0.0f;
            const float fj = (float)j;
            const float g = (lane & 1) ? -gf : gf;
#pragma unroll
            for (int r = 0; r < 4; ++r) {
                float p = exp2f(fj * l[r]);
                float pc = p * cf[r], ps = p * sf[r];
                float mpc = mg[r] * pc, mps = mg[r] * ps;
                float2 Sv = make_float2(fmaf(g, pc, mpc), fmaf(g, ps, mps));
                float2 Vv = make_float2(fmaf(-g, pc, mpc), fmaf(-g, ps, mps));
                if (r == 0 && lane == 0) { Sv.y = 0.0f; Vv.y = 0.0f; }
                S[q][r] = Sv; V[q][r] = Vv;
            }
            const float p6 = exp2f(fj * l6);
            S6[q] = p6 * (m6 + gf) * c6;
            V6[q] = p6 * (m6 - gf) * c6;
        }

        // ---- Hann 3-tap via shuffles (both chains interleaved)
#pragma unroll
        for (int q = 0; q < 2; ++q) {
            float2 b63[3], b0h[4], v1;
            b63[0] = shfl2(V[q][0], 63); b63[1] = shfl2(V[q][1], 63); b63[2] = shfl2(V[q][2], 63);
            b0h[1] = shfl2(V[q][1], 0);  b0h[2] = shfl2(V[q][2], 0);  b0h[3] = shfl2(V[q][3], 0);
            v1 = shfl2(V[q][0], 1);
            const float v255x = __shfl(V[q][3].x, 63);
#pragma unroll
            for (int r = 0; r < 4; ++r) {
                float2 vm = shfl2(V[q][r], dn);
                float2 vp = shfl2(V[q][r], up);
                if (lane == 0)  vm = (r == 0) ? make_float2(v1.x, -v1.y) : b63[r-1];
                if (lane == 63) vp = (r == 3) ? make_float2(V6[q], 0.f)  : b0h[r+1];
                H[q][r] = make_float2(0.5f*S[q][r].x - 0.25f*(vm.x + vp.x),
                                      0.5f*S[q][r].y - 0.25f*(vm.y + vp.y));
            }
            H6[q] = 0.5f*S6[q] - 0.5f*v255x;
        }

        // ---- half-size packing
#pragma unroll
        for (int q = 0; q < 2; ++q) {
#pragma unroll
            for (int r = 0; r < 4; ++r) {
                float2 Hm = shfl2(H[q][3-r], mlane);
                if (lane == 0) Hm = (r == 0) ? make_float2(H6[q], 0.f)
                                             : ((r == 1) ? H[q][3] : ((r == 2) ? H[q][2] : H[q][1]));
                float2 w = zwr[r];
                float Ar = H[q][r].x + Hm.x, Ai = H[q][r].y - Hm.y;
                float Br = H[q][r].x - Hm.x, Bi = H[q][r].y + Hm.y;
                float iwr = -w.y*Br - w.x*Bi;
                float iwi =  w.x*Br - w.y*Bi;
                Z[q][r] = make_float2((Ar + iwr)*(1.0f/512.0f), (Ai + iwi)*(1.0f/512.0f));
            }
        }

        // ---- FFT stage 0 (lane-local) -> bufA
#pragma unroll
        for (int q = 0; q < 2; ++q) {
            float2* bufA = bufA_s[wv][q];
            float2 apc = cadd(Z[q][0], Z[q][2]), amc = csub(Z[q][0], Z[q][2]);
            float2 bpd = cadd(Z[q][1], Z[q][3]);
            float2 jb = make_float2(Z[q][3].y - Z[q][1].y, Z[q][1].x - Z[q][3].x);
            const int base = lane << 2;
            bufA[PH(base + 0)] = cadd(apc, bpd);
            bufA[PH(base + 1)] = cmul(s0w1, cadd(amc, jb));
            bufA[PH(base + 2)] = cmul(s0w2, csub(apc, bpd));
            bufA[PH(base + 3)] = cmul(s0w3, csub(amc, jb));
        }
        lgkm_sync();

        // ---- FFT stage 1 (s=4): bufA -> bufB
#pragma unroll
        for (int q = 0; q < 2; ++q) {
            float2* bufA = bufA_s[wv][q];
            float2* bufB = bufB_s[wv][q];
            float2 A = bufA[PH(lane)];
            float2 B = bufA[PH(lane + 64)];
            float2 C = bufA[PH(lane + 128)];
            float2 D = bufA[PH(lane + 192)];
            float2 apc = cadd(A, C), amc = csub(A, C);
            float2 bpd = cadd(B, D);
            float2 jb = make_float2(D.y - B.y, B.x - D.x);
            const int ob = (lane & 3) + ((lane >> 2) << 4);
            bufB[PH(ob)]      = cadd(apc, bpd);
            bufB[PH(ob + 4)]  = cmul(s1w1, cadd(amc, jb));
            bufB[PH(ob + 8)]  = cmul(s1w2, csub(apc, bpd));
            bufB[PH(ob + 12)] = cmul(s1w3, csub(amc, jb));
        }
        lgkm_sync();

        // ---- FFT stage 2 (s=16): bufB -> bufA
#pragma unroll
        for (int q = 0; q < 2; ++q) {
            float2* bufA = bufA_s[wv][q];
            float2* bufB = bufB_s[wv][q];
            float2 A = bufB[PH(lane)];
            float2 B = bufB[PH(lane + 64)];
            float2 C = bufB[PH(lane + 128)];
            float2 D = bufB[PH(lane + 192)];
            float2 apc = cadd(A, C), amc = csub(A, C);
            float2 bpd = cadd(B, D);
            float2 jb = make_float2(D.y - B.y, B.x - D.x);
            const int ob = (lane & 15) + ((lane >> 4) << 6);
            bufA[PH(ob)]      = cadd(apc, bpd);
            bufA[PH(ob + 16)] = cmul(s2w1, cadd(amc, jb));
            bufA[PH(ob + 32)] = cmul(s2w2, csub(apc, bpd));
            bufA[PH(ob + 48)] = cmul(s2w3, csub(amc, jb));
        }
        lgkm_sync();

        // ---- stage 3 fused (twiddles=1, lower half only) + store
#pragma unroll
        for (int q = 0; q < 2; ++q) {
            float2* bufA = bufA_s[wv][q];
            float2 A = bufA[PH(lane)];
            float2 B = bufA[PH(lane + 64)];
            float2 C = bufA[PH(lane + 128)];
            float2 D = bufA[PH(lane + 192)];
            float2 apc = cadd(A, C), amc = csub(A, C);
            float2 bpd = cadd(B, D);
            float2 jb = make_float2(D.y - B.y, B.x - D.x);
            float2 y0 = cadd(apc, bpd);
            float2 y1 = cadd(amc, jb);
            float2* o2 = outbase + (jq[q] << 7);
            o2[lane] = y0;
            o2[lane + 64] = y1;
        }
        lgkm_sync();   // WAR guard: stage-3 reads drained before next-t stage-0 writes
    }
}

extern "C" void kernel_launch(void* const* d_in, const int* in_sizes, int n_in,
                              void* d_out, int out_size, void* d_ws, size_t ws_size,
                              hipStream_t stream)
{
    const float* sel   = (const float*)d_in[0];   // (8,32,4,4096) f32 -> [1024][4096]
    const float* items = (const float*)d_in[1];   // (4096,514) f32
    float* out = (float*)d_out;                   // [1024][32768] f32
    float* ws  = (float*)d_ws;

    float* W     = out;                  // 1024*4096 floats (scratch in d_out)
    float* Cpart = out + 4194304;        // KSPLIT*1024*NPAD floats
    float* P     = ws;                   // 4*1024*257 floats

    ksoftw<<<1024, 256, 0, stream>>>(sel, W);
    dim3 g2(16, 9, KSPLIT);
    kgemm2<<<g2, 256, 0, stream>>>(W, items, Cpart);
    ktrans<<<1024, 256, 0, stream>>>(Cpart, P);
    kres<<<8192, 256, 0, stream>>>(P, out);
}

// Round 8
// 156.271 us; speedup vs baseline: 1.1546x; 1.1546x over previous
//
#include <hip/hip_runtime.h>

#define PI_F 3.14159265358979f
#define NPAD 576
#define KSPLIT 8

__device__ __forceinline__ float2 cadd(float2 a, float2 b){ return make_float2(a.x+b.x, a.y+b.y); }
__device__ __forceinline__ float2 csub(float2 a, float2 b){ return make_float2(a.x-b.x, a.y-b.y); }
__device__ __forceinline__ float2 cmul(float2 a, float2 b){ return make_float2(a.x*b.x - a.y*b.y, a.x*b.y + a.y*b.x); }

// XOR swizzle on complex index for FFT ping-pong buffers
#define PH(i) ((i) ^ ((((unsigned)(i))>>5)&7))

// COMPILER-ONLY fence: LDS pipe is in-order per wave (buffers are wave-private),
// so cross-lane visibility needs no hardware drain — only a reorder barrier.
__device__ __forceinline__ void cfence() {
    asm volatile("" ::: "memory");
}

// ---------------- kernel A: softmax -> W (normalized weights, f32) ----------------
__global__ __launch_bounds__(256) void ksoftw(const float* __restrict__ sel,
                                              float* __restrict__ Wout)
{
    const int row = blockIdx.x;
    const int tid = threadIdx.x;
    const float4* p4 = (const float4*)(sel + (size_t)row * 4096);
    float4 v[4];
    float mx = -3.0e38f;
#pragma unroll
    for (int i = 0; i < 4; ++i) {
        v[i] = p4[tid + (i<<8)];
        mx = fmaxf(mx, fmaxf(fmaxf(v[i].x, v[i].y), fmaxf(v[i].z, v[i].w)));
    }
#pragma unroll
    for (int o = 32; o >= 1; o >>= 1) mx = fmaxf(mx, __shfl_xor(mx, o));
    __shared__ float red[8];
    const int wv = tid >> 6;
    if ((tid & 63) == 0) red[wv] = mx;
    __syncthreads();
    mx = fmaxf(fmaxf(red[0], red[1]), fmaxf(red[2], red[3]));
    float s = 0.0f;
#pragma unroll
    for (int i = 0; i < 4; ++i) {
        s += __expf(v[i].x - mx) + __expf(v[i].y - mx) + __expf(v[i].z - mx) + __expf(v[i].w - mx);
    }
#pragma unroll
    for (int o = 32; o >= 1; o >>= 1) s += __shfl_xor(s, o);
    if ((tid & 63) == 0) red[4 + wv] = s;
    __syncthreads();
    const float inv = 1.0f / (red[4] + red[5] + red[6] + red[7]);
    float4* w4 = (float4*)(Wout + (size_t)row * 4096);
#pragma unroll
    for (int i = 0; i < 4; ++i) {
        float4 e;
        e.x = __expf(v[i].x - mx) * inv;
        e.y = __expf(v[i].y - mx) * inv;
        e.z = __expf(v[i].z - mx) * inv;
        e.w = __expf(v[i].w - mx) * inv;
        w4[tid + (i<<8)] = e;
    }
}

// ---------------- kernel B: split-K GEMM  Cpart[ks] = W[:, ks] @ items[ks, :] ----------------
__global__ __launch_bounds__(256, 2) void kgemm2(const float* __restrict__ W,
                                                 const float* __restrict__ items,
                                                 float* __restrict__ Cpart)
{
    __shared__ float As[16][68];   // [k][m]
    __shared__ float Bs[16][72];   // [k][n]
    const int tid = threadIdx.x;
    const int r0 = blockIdx.x * 64;
    const int c0 = blockIdx.y * 64;
    const int k0 = blockIdx.z * (4096 / KSPLIT);

    const int ty = tid >> 4;
    const int tx = tid & 15;
    const int am = tid >> 2;
    const int ak = (tid & 3) << 2;
    const int brow = tid >> 4;
    const int bc4 = (tid & 15) << 2;
    const int bcol = c0 + bc4;

    const float* wp = W + (size_t)(r0 + am) * 4096 + k0 + ak;

    float acc[4][4] = {{0.f}};

    for (int kt = 0; kt < (4096 / KSPLIT) / 16; ++kt) {
        const int kb = kt << 4;
        const float4 a = *(const float4*)(wp + kb);
        const float* ip = items + (size_t)(k0 + kb + brow) * 514 + bcol;
        float2 b01 = (bcol     < 514) ? *(const float2*)(ip)     : make_float2(0.f, 0.f);
        float2 b23 = (bcol + 2 < 514) ? *(const float2*)(ip + 2) : make_float2(0.f, 0.f);
        __syncthreads();
        As[ak + 0][am] = a.x;
        As[ak + 1][am] = a.y;
        As[ak + 2][am] = a.z;
        As[ak + 3][am] = a.w;
        *(float4*)&Bs[brow][bc4] = make_float4(b01.x, b01.y, b23.x, b23.y);
        __syncthreads();
#pragma unroll
        for (int kk = 0; kk < 16; ++kk) {
            const float4 av = *(const float4*)&As[kk][ty << 2];
            const float4 bv = *(const float4*)&Bs[kk][tx << 2];
            acc[0][0] = fmaf(av.x, bv.x, acc[0][0]);
            acc[0][1] = fmaf(av.x, bv.y, acc[0][1]);
            acc[0][2] = fmaf(av.x, bv.z, acc[0][2]);
            acc[0][3] = fmaf(av.x, bv.w, acc[0][3]);
            acc[1][0] = fmaf(av.y, bv.x, acc[1][0]);
            acc[1][1] = fmaf(av.y, bv.y, acc[1][1]);
            acc[1][2] = fmaf(av.y, bv.z, acc[1][2]);
            acc[1][3] = fmaf(av.y, bv.w, acc[1][3]);
            acc[2][0] = fmaf(av.z, bv.x, acc[2][0]);
            acc[2][1] = fmaf(av.z, bv.y, acc[2][1]);
            acc[2][2] = fmaf(av.z, bv.z, acc[2][2]);
            acc[2][3] = fmaf(av.z, bv.w, acc[2][3]);
            acc[3][0] = fmaf(av.w, bv.x, acc[3][0]);
            acc[3][1] = fmaf(av.w, bv.y, acc[3][1]);
            acc[3][2] = fmaf(av.w, bv.z, acc[3][2]);
            acc[3][3] = fmaf(av.w, bv.w, acc[3][3]);
        }
    }

    float* cp = Cpart + (size_t)blockIdx.z * (1024 * NPAD)
                      + (size_t)(r0 + (ty << 2)) * NPAD + c0 + (tx << 2);
#pragma unroll
    for (int i = 0; i < 4; ++i) {
        *(float4*)(cp + (size_t)i * NPAD) = make_float4(acc[i][0], acc[i][1], acc[i][2], acc[i][3]);
    }
}

// ---------------- kernel B2: reduce split-K + transform -> P planes ----------------
__global__ __launch_bounds__(256) void ktrans(const float* __restrict__ Cpart,
                                              float* __restrict__ P)
{
    const int m = blockIdx.x;
    float* Lp = P;
    float* Mp = P + 1024*257;
    float* Cp = P + 2*1024*257;
    float* Sp = P + 3*1024*257;
    for (int c = threadIdx.x; c < 514; c += 256) {
        const float* cp = Cpart + (size_t)m * NPAD + c;
        float x = 0.f;
#pragma unroll
        for (int ks = 0; ks < KSPLIT; ++ks) x += cp[(size_t)ks * (1024 * NPAD)];
        if (c < 257) {
            float mm = 0.9999f / (1.0f + __expf(-x));
            int idx = m*257 + c;
            Lp[idx] = __log2f(mm);
            Mp[idx] = mm;
        } else {
            int idx = m*257 + (c - 257);
            float e2 = __expf(2.0f*x);
            float th = (e2 - 1.0f) / (e2 + 1.0f);
            float ph = PI_F * th;
            float sn, cs;
            __sincosf(ph, &sn, &cs);
            Cp[idx] = cs;
            Sp[idx] = sn;
        }
    }
}

// ---------------- kernel C: spectral + IFFT, wave-private LDS, compiler fences only ----------
// grid = 1024 items * 8 jgroups; 4 independent waves per block; each wave does 4 j-blocks.
// p = m^j advanced by multiply recurrence (p *= m^4 per t); all twiddles in registers.
__global__ __launch_bounds__(256) void kres(const float* __restrict__ P, float* __restrict__ out)
{
    const int tid = threadIdx.x;
    const int lane = tid & 63;
    const int wv = tid >> 6;
    const int item = blockIdx.x >> 3;
    const int jg = blockIdx.x & 7;

    __shared__ float2 bufA_s[4][257];
    __shared__ float2 bufB_s[4][257];
    float2* bufA = bufA_s[wv];
    float2* bufB = bufB_s[wv];

    // FFT stage twiddles e^{+2pi i idx/256} — pure functions of lane, in regs
    const float A256 = 6.283185307179586f / 256.0f;
    float2 s0w1, s0w2, s0w3, s1w1, s1w2, s1w3, s2w1, s2w2, s2w3;
    {
        float s, c;
        const int p1 = (lane >> 2) << 2;
        const int p2 = (lane >> 4) << 4;
        __sincosf(A256 * (float)lane,     &s, &c); s0w1 = make_float2(c, s);
        __sincosf(A256 * (float)(2*lane), &s, &c); s0w2 = make_float2(c, s);
        __sincosf(A256 * (float)(3*lane), &s, &c); s0w3 = make_float2(c, s);
        __sincosf(A256 * (float)p1,       &s, &c); s1w1 = make_float2(c, s);
        __sincosf(A256 * (float)(2*p1),   &s, &c); s1w2 = make_float2(c, s);
        __sincosf(A256 * (float)(3*p1),   &s, &c); s1w3 = make_float2(c, s);
        __sincosf(A256 * (float)p2,       &s, &c); s2w1 = make_float2(c, s);
        __sincosf(A256 * (float)(2*p2),   &s, &c); s2w2 = make_float2(c, s);
        __sincosf(A256 * (float)(3*p2),   &s, &c); s2w3 = make_float2(c, s);
    }
    // half-size-packing twiddles e^{+2pi i k/512}, k = lane+64r
    float2 zwr[4];
#pragma unroll
    for (int r = 0; r < 4; ++r) {
        float s, c;
        __sincosf((6.283185307179586f/512.0f) * (float)(lane + (r<<6)), &s, &c);
        zwr[r] = make_float2(c, s);
    }

    const float* Lp = P;
    const float* Mp = P + 1024*257;
    const float* Cp = P + 2*1024*257;
    const float* Sp = P + 3*1024*257;
    const int pb = item * 257;

    float l[4], mg[4], cf[4], sf[4];
#pragma unroll
    for (int r = 0; r < 4; ++r) {
        int c = lane + (r<<6);
        l[r]  = Lp[pb + c];
        mg[r] = Mp[pb + c];
        cf[r] = Cp[pb + c];
        sf[r] = Sp[pb + c];
    }
    const float l6 = Lp[pb + 256];
    const float m6 = Mp[pb + 256];
    const float c6 = Cp[pb + 256];

    // p = m^j via recurrence: j = j0 + 4t  ->  p *= m^4 each t
    const int j0 = jg*16 + wv;
    float p[4], m4[4];
#pragma unroll
    for (int r = 0; r < 4; ++r) {
        float m2 = mg[r] * mg[r];
        m4[r] = m2 * m2;
        p[r] = exp2f((float)j0 * l[r]);
    }
    float p6 = exp2f((float)j0 * l6);
    const float m6_2 = m6 * m6;
    const float m6_4 = m6_2 * m6_2;

    float2* outbase = (float2*)out + (size_t)item * 16384;

    for (int t = 0; t < 4; ++t) {
        const int j = j0 + (t<<2);
        const float gf = (j > 0) ? 1.0f : 0.0f;
        const float g = (lane & 1) ? -gf : gf;   // (-1)^c, c = lane+64r (64r even)

        // ---- phase 1: S (regs) and V -> bufB
        float2 S[4];
#pragma unroll
        for (int r = 0; r < 4; ++r) {
            int c = lane + (r<<6);
            float pc = p[r] * cf[r], ps = p[r] * sf[r];
            float mpc = mg[r] * pc, mps = mg[r] * ps;
            float2 Sv = make_float2(fmaf(g, pc, mpc), fmaf(g, ps, mps));
            float2 Vv = make_float2(fmaf(-g, pc, mpc), fmaf(-g, ps, mps));
            if (c == 0) { Sv.y = 0.0f; Vv.y = 0.0f; }   // DC imag dropped
            S[r] = Sv;
            bufB[c] = Vv;
        }
        const float S6 = p6 * (m6 + gf) * c6;            // bin 256 real
        const float V6 = p6 * (m6 - gf) * c6;
        if (lane == 0) bufB[256] = make_float2(V6, 0.0f);
        cfence();

        // ---- phase 2: H[c] = 0.5 S - 0.25 (V[c-1]+V[c+1]) -> bufA
#pragma unroll
        for (int r = 0; r < 4; ++r) {
            int c = lane + (r<<6);
            float2 Vm;
            if (c == 0) { float2 v1 = bufB[1]; Vm = make_float2(v1.x, -v1.y); }
            else Vm = bufB[c-1];
            float2 Vp = bufB[c+1];
            bufA[c] = make_float2(0.5f*S[r].x - 0.25f*(Vm.x + Vp.x),
                                  0.5f*S[r].y - 0.25f*(Vm.y + Vp.y));
        }
        if (lane == 0) {
            float2 v255 = bufB[255];
            bufA[256] = make_float2(0.5f*S6 - 0.5f*v255.x, 0.0f);
        }
        cfence();

        // ---- phase 3: half-size packing -> Z (regs)
        float2 Z[4];
#pragma unroll
        for (int r = 0; r < 4; ++r) {
            int k = lane + (r<<6);
            float2 Hk = bufA[k];
            float2 Hm = bufA[256-k];
            float2 w = zwr[r];
            float Ar = Hk.x + Hm.x, Ai = Hk.y - Hm.y;
            float Br = Hk.x - Hm.x, Bi = Hk.y + Hm.y;
            float iwr = -w.y*Br - w.x*Bi;
            float iwi =  w.x*Br - w.y*Bi;
            Z[r] = make_float2((Ar + iwr)*(1.0f/512.0f), (Ai + iwi)*(1.0f/512.0f));
        }
        cfence();

        // ---- FFT stage 0 (lane-local, elements k=lane+64r) -> bufB
        {
            float2 apc = cadd(Z[0], Z[2]), amc = csub(Z[0], Z[2]);
            float2 bpd = cadd(Z[1], Z[3]);
            float2 jb = make_float2(Z[3].y - Z[1].y, Z[1].x - Z[3].x);
            const int base = lane << 2;
            bufB[PH(base + 0)] = cadd(apc, bpd);
            bufB[PH(base + 1)] = cmul(s0w1, cadd(amc, jb));
            bufB[PH(base + 2)] = cmul(s0w2, csub(apc, bpd));
            bufB[PH(base + 3)] = cmul(s0w3, csub(amc, jb));
        }
        cfence();

        // ---- FFT stage 1 (s=4): bufB -> bufA
        {
            float2 A = bufB[PH(lane)];
            float2 B = bufB[PH(lane + 64)];
            float2 C = bufB[PH(lane + 128)];
            float2 D = bufB[PH(lane + 192)];
            float2 apc = cadd(A, C), amc = csub(A, C);
            float2 bpd = cadd(B, D);
            float2 jb = make_float2(D.y - B.y, B.x - D.x);
            const int ob = (lane & 3) + ((lane >> 2) << 4);
            bufA[PH(ob)]      = cadd(apc, bpd);
            bufA[PH(ob + 4)]  = cmul(s1w1, cadd(amc, jb));
            bufA[PH(ob + 8)]  = cmul(s1w2, csub(apc, bpd));
            bufA[PH(ob + 12)] = cmul(s1w3, csub(amc, jb));
        }
        cfence();

        // ---- FFT stage 2 (s=16): bufA -> bufB
        {
            float2 A = bufA[PH(lane)];
            float2 B = bufA[PH(lane + 64)];
            float2 C = bufA[PH(lane + 128)];
            float2 D = bufA[PH(lane + 192)];
            float2 apc = cadd(A, C), amc = csub(A, C);
            float2 bpd = cadd(B, D);
            float2 jb = make_float2(D.y - B.y, B.x - D.x);
            const int ob = (lane & 15) + ((lane >> 4) << 6);
            bufB[PH(ob)]      = cadd(apc, bpd);
            bufB[PH(ob + 16)] = cmul(s2w1, cadd(amc, jb));
            bufB[PH(ob + 32)] = cmul(s2w2, csub(apc, bpd));
            bufB[PH(ob + 48)] = cmul(s2w3, csub(amc, jb));
        }
        cfence();

        // ---- stage 3 fused (twiddles=1, lower half only) + store
        {
            float2 A = bufB[PH(lane)];
            float2 B = bufB[PH(lane + 64)];
            float2 C = bufB[PH(lane + 128)];
            float2 D = bufB[PH(lane + 192)];
            float2 apc = cadd(A, C), amc = csub(A, C);
            float2 bpd = cadd(B, D);
            float2 jb = make_float2(D.y - B.y, B.x - D.x);
            float2 y0 = cadd(apc, bpd);
            float2 y1 = cadd(amc, jb);
            float2* o2 = outbase + (j << 7);
            o2[lane] = y0;
            o2[lane + 64] = y1;
        }
        cfence();

        // advance p = m^j by m^4 for next t
#pragma unroll
        for (int r = 0; r < 4; ++r) p[r] *= m4[r];
        p6 *= m6_4;
    }
}

extern "C" void kernel_launch(void* const* d_in, const int* in_sizes, int n_in,
                              void* d_out, int out_size, void* d_ws, size_t ws_size,
                              hipStream_t stream)
{
    const float* sel   = (const float*)d_in[0];   // (8,32,4,4096) f32 -> [1024][4096]
    const float* items = (const float*)d_in[1];   // (4096,514) f32
    float* out = (float*)d_out;                   // [1024][32768] f32
    float* ws  = (float*)d_ws;

    float* W     = out;                  // 1024*4096 floats (scratch in d_out)
    float* Cpart = out + 4194304;        // KSPLIT*1024*NPAD floats
    float* P     = ws;                   // 4*1024*257 floats

    ksoftw<<<1024, 256, 0, stream>>>(sel, W);
    dim3 g2(16, 9, KSPLIT);
    kgemm2<<<g2, 256, 0, stream>>>(W, items, Cpart);
    ktrans<<<1024, 256, 0, stream>>>(Cpart, P);
    kres<<<8192, 256, 0, stream>>>(P, out);
}

// Round 9
// 133.108 us; speedup vs baseline: 1.3555x; 1.1740x over previous
//
#include <hip/hip_runtime.h>

#define PI_F 3.14159265358979f
#define CAP 256

__device__ __forceinline__ float2 cadd(float2 a, float2 b){ return make_float2(a.x+b.x, a.y+b.y); }
__device__ __forceinline__ float2 csub(float2 a, float2 b){ return make_float2(a.x-b.x, a.y-b.y); }
__device__ __forceinline__ float2 cmul(float2 a, float2 b){ return make_float2(a.x*b.x - a.y*b.y, a.x*b.y + a.y*b.x); }

// XOR swizzle on complex index for FFT ping-pong buffers
#define PH(i) ((i) ^ ((((unsigned)(i))>>5)&7))

// COMPILER-ONLY fence: LDS pipe is in-order per wave (buffers are wave-private),
// so cross-lane visibility needs no hardware drain — only a reorder barrier.
__device__ __forceinline__ void cfence() {
    asm volatile("" ::: "memory");
}

// ---------------- kernel A: per-row softmax stats (max, 1/sumexp) ----------------
__global__ __launch_bounds__(256) void ksoft(const float* __restrict__ sel,
                                             float* __restrict__ rowmax,
                                             float* __restrict__ rowinv)
{
    const int row = blockIdx.x;
    const int tid = threadIdx.x;
    const float4* p4 = (const float4*)(sel + (size_t)row * 4096);
    float4 v[4];
    float mx = -3.0e38f;
#pragma unroll
    for (int i = 0; i < 4; ++i) {
        v[i] = p4[tid + (i<<8)];
        mx = fmaxf(mx, fmaxf(fmaxf(v[i].x, v[i].y), fmaxf(v[i].z, v[i].w)));
    }
#pragma unroll
    for (int o = 32; o >= 1; o >>= 1) mx = fmaxf(mx, __shfl_xor(mx, o));
    __shared__ float red[8];
    const int wv = tid >> 6;
    if ((tid & 63) == 0) red[wv] = mx;
    __syncthreads();
    mx = fmaxf(fmaxf(red[0], red[1]), fmaxf(red[2], red[3]));
    float s = 0.0f;
#pragma unroll
    for (int i = 0; i < 4; ++i) {
        s += __expf(v[i].x - mx) + __expf(v[i].y - mx) + __expf(v[i].z - mx) + __expf(v[i].w - mx);
    }
#pragma unroll
    for (int o = 32; o >= 1; o >>= 1) s += __shfl_xor(s, o);
    if ((tid & 63) == 0) red[4 + wv] = s;
    __syncthreads();
    if (tid == 0) {
        rowmax[row] = mx;
        rowinv[row] = 1.0f / (red[4] + red[5] + red[6] + red[7]);
    }
}

// ---------------- kernel A2: W^T[k][m] = softmax weight, tiled transpose ----------------
// grid (64 k-tiles, 16 m-tiles), 256 threads, 64x64 tile via LDS.
__global__ __launch_bounds__(256) void kT(const float* __restrict__ sel,
                                          const float* __restrict__ rowmax,
                                          const float* __restrict__ rowinv,
                                          float* __restrict__ WT)
{
    __shared__ float tile[64][65];
    __shared__ float smx[64], sinv[64];
    const int t = threadIdx.x;
    const int k0 = blockIdx.x * 64;
    const int m0 = blockIdx.y * 64;

    if (t < 64) { smx[t] = rowmax[m0 + t]; sinv[t] = rowinv[m0 + t]; }
    __syncthreads();

    const int m_l = t >> 4;            // 0..15
    const int k_l4 = (t & 15) << 2;    // 0,4,..,60
#pragma unroll
    for (int i = 0; i < 4; ++i) {
        const int ml = m_l + (i << 4);
        const float mxv = smx[ml], invv = sinv[ml];
        float4 v = *(const float4*)(sel + (size_t)(m0 + ml) * 4096 + k0 + k_l4);
        tile[k_l4 + 0][ml] = __expf(v.x - mxv) * invv;
        tile[k_l4 + 1][ml] = __expf(v.y - mxv) * invv;
        tile[k_l4 + 2][ml] = __expf(v.z - mxv) * invv;
        tile[k_l4 + 3][ml] = __expf(v.w - mxv) * invv;
    }
    __syncthreads();

    const int k_l = t >> 2;            // 0..63
    const int mb = (t & 3) << 2;       // 0,4,8,12
#pragma unroll
    for (int i = 0; i < 4; ++i) {
        const int ml = mb + (i << 4);
        float4 w = make_float4(tile[k_l][ml], tile[k_l][ml+1], tile[k_l][ml+2], tile[k_l][ml+3]);
        *(float4*)(WT + (size_t)(k0 + k_l) * 1024 + m0 + ml) = w;
    }
}

// ---------------- kernel B: build per-column nonzero lists of items (deterministic) -----
// grid = 514 blocks (one per column), 4 waves; wave q scans k in [q*1024, q*1024+1024).
__global__ __launch_bounds__(256) void kfill(const float* __restrict__ items,
                                             int* __restrict__ kidx,
                                             float* __restrict__ kval,
                                             int* __restrict__ ncol)
{
    const int c = blockIdx.x;
    const int t = threadIdx.x;
    const int wv = t >> 6;
    const int lane = t & 63;
    __shared__ int wcnt[4];

    const int kc0 = wv << 10;
    float vv[16];
    int cnt = 0;
#pragma unroll
    for (int it = 0; it < 16; ++it) {
        const int k = kc0 + (it << 6) + lane;
        const float v = items[(size_t)k * 514 + c];
        vv[it] = v;
        unsigned long long mb = __ballot(v != 0.0f);
        cnt += __popcll(mb);
    }
    if (lane == 0) wcnt[wv] = cnt;
    __syncthreads();

    int base = 0;
#pragma unroll
    for (int q = 0; q < 4; ++q) if (q < wv) base += wcnt[q];

    const unsigned long long ltmask = (lane == 63) ? 0x7fffffffffffffffull
                                                   : ((1ull << lane) - 1ull);
#pragma unroll
    for (int it = 0; it < 16; ++it) {
        const float v = vv[it];
        const bool nz = (v != 0.0f);
        unsigned long long mb = __ballot(nz);
        if (nz) {
            const int slot = base + __popcll(mb & ltmask);
            if (slot < CAP) {
                kidx[c * CAP + slot] = kc0 + (it << 6) + lane;
                kval[c * CAP + slot] = v;
            }
        }
        base += __popcll(mb);
    }
    if (t == 0) ncol[c] = wcnt[0] + wcnt[1] + wcnt[2] + wcnt[3];
}

// ---------------- kernel B2: sparse matmul + transform -> P planes ----------------
// grid (514 c, 4 mchunks); thread owns one m; ~41 iterations of broadcast (k,v) x W^T row.
// P layout (floats): L[1024*257] | M[1024*257] | COS[1024*257] | SIN[1024*257]
__global__ __launch_bounds__(256) void kspmm(const float* __restrict__ WT,
                                             const int* __restrict__ kidx,
                                             const float* __restrict__ kval,
                                             const int* __restrict__ ncol,
                                             float* __restrict__ P)
{
    const int c = blockIdx.x;
    const int m = (blockIdx.y << 8) + threadIdx.x;
    const int nn = min(ncol[c], CAP);
    const int* ki = kidx + c * CAP;
    const float* kv = kval + c * CAP;

    float acc = 0.0f;
    int i = 0;
    for (; i + 4 <= nn; i += 4) {
        const int k0 = ki[i], k1 = ki[i+1], k2 = ki[i+2], k3 = ki[i+3];
        const float v0 = kv[i], v1 = kv[i+1], v2 = kv[i+2], v3 = kv[i+3];
        const float w0 = WT[(size_t)k0 * 1024 + m];
        const float w1 = WT[(size_t)k1 * 1024 + m];
        const float w2 = WT[(size_t)k2 * 1024 + m];
        const float w3 = WT[(size_t)k3 * 1024 + m];
        acc = fmaf(v0, w0, acc);
        acc = fmaf(v1, w1, acc);
        acc = fmaf(v2, w2, acc);
        acc = fmaf(v3, w3, acc);
    }
    for (; i < nn; ++i) {
        acc = fmaf(kv[i], WT[(size_t)ki[i] * 1024 + m], acc);
    }

    float* Lp = P;
    float* Mp = P + 1024*257;
    float* Cp = P + 2*1024*257;
    float* Sp = P + 3*1024*257;
    const float x = acc;
    if (c < 257) {
        float mm = 0.9999f / (1.0f + __expf(-x));
        const int idx = m * 257 + c;
        Lp[idx] = __log2f(mm);
        Mp[idx] = mm;
    } else {
        const int idx = m * 257 + (c - 257);
        float e2 = __expf(2.0f * x);
        float th = (e2 - 1.0f) / (e2 + 1.0f);
        float ph = PI_F * th;
        float sn, cs;
        __sincosf(ph, &sn, &cs);
        Cp[idx] = cs;
        Sp[idx] = sn;
    }
}

// ---------------- kernel C: spectral + IFFT, wave-private LDS, compiler fences only ----------
// (unchanged from R8 — 96 us known-good)
__global__ __launch_bounds__(256) void kres(const float* __restrict__ P, float* __restrict__ out)
{
    const int tid = threadIdx.x;
    const int lane = tid & 63;
    const int wv = tid >> 6;
    const int item = blockIdx.x >> 3;
    const int jg = blockIdx.x & 7;

    __shared__ float2 bufA_s[4][257];
    __shared__ float2 bufB_s[4][257];
    float2* bufA = bufA_s[wv];
    float2* bufB = bufB_s[wv];

    const float A256 = 6.283185307179586f / 256.0f;
    float2 s0w1, s0w2, s0w3, s1w1, s1w2, s1w3, s2w1, s2w2, s2w3;
    {
        float s, c;
        const int p1 = (lane >> 2) << 2;
        const int p2 = (lane >> 4) << 4;
        __sincosf(A256 * (float)lane,     &s, &c); s0w1 = make_float2(c, s);
        __sincosf(A256 * (float)(2*lane), &s, &c); s0w2 = make_float2(c, s);
        __sincosf(A256 * (float)(3*lane), &s, &c); s0w3 = make_float2(c, s);
        __sincosf(A256 * (float)p1,       &s, &c); s1w1 = make_float2(c, s);
        __sincosf(A256 * (float)(2*p1),   &s, &c); s1w2 = make_float2(c, s);
        __sincosf(A256 * (float)(3*p1),   &s, &c); s1w3 = make_float2(c, s);
        __sincosf(A256 * (float)p2,       &s, &c); s2w1 = make_float2(c, s);
        __sincosf(A256 * (float)(2*p2),   &s, &c); s2w2 = make_float2(c, s);
        __sincosf(A256 * (float)(3*p2),   &s, &c); s2w3 = make_float2(c, s);
    }
    float2 zwr[4];
#pragma unroll
    for (int r = 0; r < 4; ++r) {
        float s, c;
        __sincosf((6.283185307179586f/512.0f) * (float)(lane + (r<<6)), &s, &c);
        zwr[r] = make_float2(c, s);
    }

    const float* Lp = P;
    const float* Mp = P + 1024*257;
    const float* Cp = P + 2*1024*257;
    const float* Sp = P + 3*1024*257;
    const int pb = item * 257;

    float l[4], mg[4], cf[4], sf[4];
#pragma unroll
    for (int r = 0; r < 4; ++r) {
        int c = lane + (r<<6);
        l[r]  = Lp[pb + c];
        mg[r] = Mp[pb + c];
        cf[r] = Cp[pb + c];
        sf[r] = Sp[pb + c];
    }
    const float l6 = Lp[pb + 256];
    const float m6 = Mp[pb + 256];
    const float c6 = Cp[pb + 256];

    const int j0 = jg*16 + wv;
    float p[4], m4[4];
#pragma unroll
    for (int r = 0; r < 4; ++r) {
        float m2 = mg[r] * mg[r];
        m4[r] = m2 * m2;
        p[r] = exp2f((float)j0 * l[r]);
    }
    float p6 = exp2f((float)j0 * l6);
    const float m6_2 = m6 * m6;
    const float m6_4 = m6_2 * m6_2;

    float2* outbase = (float2*)out + (size_t)item * 16384;

    for (int t = 0; t < 4; ++t) {
        const int j = j0 + (t<<2);
        const float gf = (j > 0) ? 1.0f : 0.0f;
        const float g = (lane & 1) ? -gf : gf;

        float2 S[4];
#pragma unroll
        for (int r = 0; r < 4; ++r) {
            int c = lane + (r<<6);
            float pc = p[r] * cf[r], ps = p[r] * sf[r];
            float mpc = mg[r] * pc, mps = mg[r] * ps;
            float2 Sv = make_float2(fmaf(g, pc, mpc), fmaf(g, ps, mps));
            float2 Vv = make_float2(fmaf(-g, pc, mpc), fmaf(-g, ps, mps));
            if (c == 0) { Sv.y = 0.0f; Vv.y = 0.0f; }
            S[r] = Sv;
            bufB[c] = Vv;
        }
        const float S6 = p6 * (m6 + gf) * c6;
        const float V6 = p6 * (m6 - gf) * c6;
        if (lane == 0) bufB[256] = make_float2(V6, 0.0f);
        cfence();

#pragma unroll
        for (int r = 0; r < 4; ++r) {
            int c = lane + (r<<6);
            float2 Vm;
            if (c == 0) { float2 v1 = bufB[1]; Vm = make_float2(v1.x, -v1.y); }
            else Vm = bufB[c-1];
            float2 Vp = bufB[c+1];
            bufA[c] = make_float2(0.5f*S[r].x - 0.25f*(Vm.x + Vp.x),
                                  0.5f*S[r].y - 0.25f*(Vm.y + Vp.y));
        }
        if (lane == 0) {
            float2 v255 = bufB[255];
            bufA[256] = make_float2(0.5f*S6 - 0.5f*v255.x, 0.0f);
        }
        cfence();

        float2 Z[4];
#pragma unroll
        for (int r = 0; r < 4; ++r) {
            int k = lane + (r<<6);
            float2 Hk = bufA[k];
            float2 Hm = bufA[256-k];
            float2 w = zwr[r];
            float Ar = Hk.x + Hm.x, Ai = Hk.y - Hm.y;
            float Br = Hk.x - Hm.x, Bi = Hk.y + Hm.y;
            float iwr = -w.y*Br - w.x*Bi;
            float iwi =  w.x*Br - w.y*Bi;
            Z[r] = make_float2((Ar + iwr)*(1.0f/512.0f), (Ai + iwi)*(1.0f/512.0f));
        }
        cfence();

        {
            float2 apc = cadd(Z[0], Z[2]), amc = csub(Z[0], Z[2]);
            float2 bpd = cadd(Z[1], Z[3]);
            float2 jb = make_float2(Z[3].y - Z[1].y, Z[1].x - Z[3].x);
            const int base = lane << 2;
            bufB[PH(base + 0)] = cadd(apc, bpd);
            bufB[PH(base + 1)] = cmul(s0w1, cadd(amc, jb));
            bufB[PH(base + 2)] = cmul(s0w2, csub(apc, bpd));
            bufB[PH(base + 3)] = cmul(s0w3, csub(amc, jb));
        }
        cfence();

        {
            float2 A = bufB[PH(lane)];
            float2 B = bufB[PH(lane + 64)];
            float2 C = bufB[PH(lane + 128)];
            float2 D = bufB[PH(lane + 192)];
            float2 apc = cadd(A, C), amc = csub(A, C);
            float2 bpd = cadd(B, D);
            float2 jb = make_float2(D.y - B.y, B.x - D.x);
            const int ob = (lane & 3) + ((lane >> 2) << 4);
            bufA[PH(ob)]      = cadd(apc, bpd);
            bufA[PH(ob + 4)]  = cmul(s1w1, cadd(amc, jb));
            bufA[PH(ob + 8)]  = cmul(s1w2, csub(apc, bpd));
            bufA[PH(ob + 12)] = cmul(s1w3, csub(amc, jb));
        }
        cfence();

        {
            float2 A = bufA[PH(lane)];
            float2 B = bufA[PH(lane + 64)];
            float2 C = bufA[PH(lane + 128)];
            float2 D = bufA[PH(lane + 192)];
            float2 apc = cadd(A, C), amc = csub(A, C);
            float2 bpd = cadd(B, D);
            float2 jb = make_float2(D.y - B.y, B.x - D.x);
            const int ob = (lane & 15) + ((lane >> 4) << 6);
            bufB[PH(ob)]      = cadd(apc, bpd);
            bufB[PH(ob + 16)] = cmul(s2w1, cadd(amc, jb));
            bufB[PH(ob + 32)] = cmul(s2w2, csub(apc, bpd));
            bufB[PH(ob + 48)] = cmul(s2w3, csub(amc, jb));
        }
        cfence();

        {
            float2 A = bufB[PH(lane)];
            float2 B = bufB[PH(lane + 64)];
            float2 C = bufB[PH(lane + 128)];
            float2 D = bufB[PH(lane + 192)];
            float2 apc = cadd(A, C), amc = csub(A, C);
            float2 bpd = cadd(B, D);
            float2 jb = make_float2(D.y - B.y, B.x - D.x);
            float2 y0 = cadd(apc, bpd);
            float2 y1 = cadd(amc, jb);
            float2* o2 = outbase + (j << 7);
            o2[lane] = y0;
            o2[lane + 64] = y1;
        }
        cfence();

#pragma unroll
        for (int r = 0; r < 4; ++r) p[r] *= m4[r];
        p6 *= m6_4;
    }
}

extern "C" void kernel_launch(void* const* d_in, const int* in_sizes, int n_in,
                              void* d_out, int out_size, void* d_ws, size_t ws_size,
                              hipStream_t stream)
{
    const float* sel   = (const float*)d_in[0];   // (8,32,4,4096) f32 -> [1024][4096]
    const float* items = (const float*)d_in[1];   // (4096,514) f32
    float* out = (float*)d_out;                   // [1024][32768] f32
    float* ws  = (float*)d_ws;

    // Scratch in d_out (all dead before kres rewrites out):
    float* WT     = out;                          // 4096*1024 = 4,194,304 f
    float* rowmax = out + 4194304;                // 1024
    float* rowinv = out + 4195328;                // 1024
    int*   ncol   = (int*)(out + 4196352);        // 514
    int*   kidx   = (int*)(out + 4196866);        // 514*CAP = 131,584
    float* kval   = (float*)(out + 4196866 + 514*CAP);  // 131,584
    // P lives in ws (proven size from prior rounds): 4*1024*257 floats
    float* P      = ws;

    ksoft<<<1024, 256, 0, stream>>>(sel, rowmax, rowinv);
    kT<<<dim3(64, 16), 256, 0, stream>>>(sel, rowmax, rowinv, WT);
    kfill<<<514, 256, 0, stream>>>(items, kidx, kval, ncol);
    kspmm<<<dim3(514, 4), 256, 0, stream>>>(WT, kidx, kval, ncol, P);
    kres<<<8192, 256, 0, stream>>>(P, out);
}